// Round 14
// baseline (5618.745 us; speedup 1.0000x reference)
//
#include <hip/hip_runtime.h>
#include <hip/hip_bf16.h>
#include <math.h>

#define B_ 16
#define T_ 512
#define C_ 1024
#define H_ 16
#define D_ 64
#define F_ 4096
#define L_ 8
#define M_ (B_*T_)   // 8192 rows

typedef __hip_bfloat16 bf16;
typedef __attribute__((ext_vector_type(8))) short short8;
typedef __attribute__((ext_vector_type(4))) float f32x4;

__device__ __forceinline__ short f2bs(float x){
  union { __hip_bfloat16 h; short s; } u;
  u.h = __float2bfloat16(x);
  return u.s;
}
__device__ __forceinline__ float bs2f(unsigned short s){
  union { float f; unsigned u; } v; v.u = ((unsigned)s) << 16; return v.f;
}

// ---------------- x f32 -> h bf16 ----------------
__global__ __launch_bounds__(256) void cvt_x(const float* __restrict__ x, bf16* __restrict__ h){
  int i = blockIdx.x*256 + threadIdx.x;
  float4 v = reinterpret_cast<const float4*>(x)[i];
  ushort4 o;
  o.x = (unsigned short)f2bs(v.x); o.y = (unsigned short)f2bs(v.y);
  o.z = (unsigned short)f2bs(v.z); o.w = (unsigned short)f2bs(v.w);
  reinterpret_cast<ushort4*>(h)[i] = o;
}

// ---------------- weight transpose+convert: W[K,N] f32 -> Wt[N,K] bf16 ----------------
__global__ __launch_bounds__(256) void convert_w(
    const float* __restrict__ Wq, const float* __restrict__ Wk,
    const float* __restrict__ Wv, const float* __restrict__ Wo,
    const float* __restrict__ W1, const float* __restrict__ W2,
    bf16* __restrict__ slab)
{
  __shared__ float t[32][33];
  int bid = blockIdx.x;
  const float* src; bf16* dst; int K, N, tile;
  if (bid < 4096) {
    int m = bid >> 10;
    src = (m==0)?Wq:(m==1)?Wk:(m==2)?Wv:Wo;
    dst = slab + (size_t)m*C_*C_;
    K = C_; N = C_; tile = bid & 1023;
  } else if (bid < 8192) {
    src = W1; dst = slab + (size_t)4*C_*C_; K = C_; N = F_; tile = bid - 4096;
  } else {
    src = W2; dst = slab + (size_t)4*C_*C_ + (size_t)C_*F_; K = F_; N = C_; tile = bid - 8192;
  }
  int tilesN = N >> 5;
  int tk = tile / tilesN, tn = tile % tilesN;
  int r = threadIdx.x >> 5, c = threadIdx.x & 31;
  #pragma unroll
  for (int i=0;i<4;i++)
    t[r + i*8][c] = src[(size_t)(tk*32 + r + i*8)*N + tn*32 + c];
  __syncthreads();
  #pragma unroll
  for (int i=0;i<4;i++)
    dst[(size_t)(tn*32 + r + i*8)*K + tk*32 + c] = __float2bfloat16(t[c][r + i*8]);
}

// ---------------- LayerNorm on bf16 residual (+optional bf16 split-K partial fold) ----------------
__global__ __launch_bounds__(256) void ln_k(bf16* __restrict__ h,
    const bf16* __restrict__ p0, const bf16* __restrict__ p1, int hasP,
    const float* __restrict__ g, const float* __restrict__ be, bf16* __restrict__ out)
{
  int row = blockIdx.x;
  int tid = threadIdx.x;
  int w = tid >> 6, lane = tid & 63;
  size_t base = (size_t)row*C_;
  ushort4 hv = reinterpret_cast<const ushort4*>(h + base)[tid];
  float vx = bs2f(hv.x), vy = bs2f(hv.y), vz = bs2f(hv.z), vw = bs2f(hv.w);
  if (hasP){
    ushort4 a = reinterpret_cast<const ushort4*>(p0 + base)[tid];
    ushort4 b = reinterpret_cast<const ushort4*>(p1 + base)[tid];
    vx += bs2f(a.x) + bs2f(b.x); vy += bs2f(a.y) + bs2f(b.y);
    vz += bs2f(a.z) + bs2f(b.z); vw += bs2f(a.w) + bs2f(b.w);
    ushort4 hw;
    hw.x = (unsigned short)f2bs(vx); hw.y = (unsigned short)f2bs(vy);
    hw.z = (unsigned short)f2bs(vz); hw.w = (unsigned short)f2bs(vw);
    reinterpret_cast<ushort4*>(h + base)[tid] = hw;
  }
  float s = vx+vy+vz+vw;
  float ss = vx*vx+vy*vy+vz*vz+vw*vw;
  #pragma unroll
  for (int o=32;o>=1;o>>=1){ s += __shfl_xor(s,o); ss += __shfl_xor(ss,o); }
  __shared__ float sa[4], sb[4];
  if (lane==0){ sa[w]=s; sb[w]=ss; }
  __syncthreads();
  s  = sa[0]+sa[1]+sa[2]+sa[3];
  ss = sb[0]+sb[1]+sb[2]+sb[3];
  float mean = s * (1.0f/C_);
  float var  = ss * (1.0f/C_) - mean*mean;
  float rs = rsqrtf(var + 1e-5f);
  float4 gv = reinterpret_cast<const float4*>(g)[tid];
  float4 bv = reinterpret_cast<const float4*>(be)[tid];
  ushort4 o;
  o.x = (unsigned short)f2bs((vx-mean)*rs*gv.x + bv.x);
  o.y = (unsigned short)f2bs((vy-mean)*rs*gv.y + bv.y);
  o.z = (unsigned short)f2bs((vz-mean)*rs*gv.z + bv.z);
  o.w = (unsigned short)f2bs((vw-mean)*rs*gv.w + bv.w);
  reinterpret_cast<ushort4*>(out + base)[tid] = o;
}

// ---------------- 256x256 GEMM, LDS-FREE: fragments direct from L2 ----------------
// No barriers, no staging, no LDS. Waves free-run; compiler schedules; L2 serves reuse
// (A-panel/B-tile are L2-scale, XCD-chunked block order keeps them hot).
// EPI: 0 = bf16+bias, 1 = tanh-GELU bf16+bias, 2 = bf16 partial store (+bias when kz==0)
template<int EPI, int QKV3>
__global__ __launch_bounds__(512) void gemmd_k(
    const bf16* __restrict__ A, int lda,
    const bf16* __restrict__ Bt, int ldb,
    const float* __restrict__ b0, const float* __restrict__ b1v,
    const float* __restrict__ b2v, int addbias,
    void* __restrict__ outp, int N, int Ksub)
{
  const int tid = threadIdx.x, lane = tid & 63;
  const int w = tid >> 6, wr = w >> 2, wc = w & 3;
  const int r16 = lane & 15, g = lane >> 4;

  // bijective XCD swizzle (all grids here have nwg % 8 == 0); row-major decode keeps
  // blocks sharing an A-panel consecutive within an XCD chunk.
  int bid = blockIdx.y * gridDim.x + blockIdx.x;
  int cpx = (gridDim.x * gridDim.y) >> 3;
  int swz = (bid & 7) * cpx + (bid >> 3);
  int tn = swz % gridDim.x, tm = swz / gridDim.x;
  const int R0 = tm * 256, C0 = tn * 256;
  const int kz = blockIdx.z;
  const int KT = Ksub >> 6;

  // per-lane fragment base pointers (k-col base g*8 folded in)
  const bf16* aBase = A  + (size_t)kz*Ksub + (size_t)(R0 + wr*64 + r16)*lda + g*8;
  const bf16* bBase = Bt + (size_t)kz*Ksub + (size_t)(C0 + wc*32 + r16)*ldb + g*8;

  const f32x4 fz = {0.f,0.f,0.f,0.f};
  f32x4 acc[8][4];
  #pragma unroll
  for (int m=0;m<8;m++){
    #pragma unroll
    for (int n=0;n<4;n++) acc[m][n] = fz;
  }

  #pragma unroll 2
  for (int kt=0; kt<KT; ++kt){
    short8 bA[2][2][2];
    #pragma unroll
    for (int nh=0;nh<2;nh++)
      #pragma unroll
      for (int n=0;n<2;n++)
        #pragma unroll
        for (int k=0;k<2;k++)
          bA[nh][n][k] = *reinterpret_cast<const short8*>(
              bBase + (size_t)(nh*128 + n*16)*ldb + kt*64 + k*32);
    #pragma unroll
    for (int mh=0; mh<2; ++mh){
      short8 af[4][2];
      #pragma unroll
      for (int m=0;m<4;m++)
        #pragma unroll
        for (int k=0;k<2;k++)
          af[m][k] = *reinterpret_cast<const short8*>(
              aBase + (size_t)(mh*128 + m*16)*lda + kt*64 + k*32);
      #pragma unroll
      for (int k=0;k<2;k++)
        #pragma unroll
        for (int m=0;m<4;m++)
          #pragma unroll
          for (int nh=0;nh<2;nh++)
            #pragma unroll
            for (int n=0;n<2;n++)
              acc[mh*4+m][nh*2+n] = __builtin_amdgcn_mfma_f32_16x16x32_bf16(
                  af[m][k], bA[nh][n][k], acc[mh*4+m][nh*2+n], 0,0,0);
    }
  }

  // epilogue (identical to verified gemm8)
  int sel = C0 >> 10;
  const float* bp = QKV3 ? (sel==0 ? b0 : (sel==1 ? b1v : b2v)) : b0;
  int cb0 = QKV3 ? (C0 & 1023) : C0;
  int ab = addbias && (kz == 0);
  #pragma unroll
  for (int mh=0; mh<2; mh++){
    #pragma unroll
    for (int m=0;m<4;m++){
      #pragma unroll
      for (int nh=0; nh<2; nh++){
        #pragma unroll
        for (int n=0;n<2;n++){
          int colrel = nh*128 + wc*32 + n*16 + r16;
          int col = C0 + colrel;
          float bb = ab ? bp[cb0 + colrel] : 0.f;
          #pragma unroll
          for (int r=0;r<4;r++){
            int row = R0 + mh*128 + wr*64 + m*16 + g*4 + r;
            float vv = acc[mh*4+m][nh*2+n][r] + bb;
            if (EPI==0){
              ((bf16*)outp)[(size_t)row*N + col] = __float2bfloat16(vv);
            } else if (EPI==1){
              float z = 0.7978845608f*(vv + 0.044715f*vv*vv*vv);
              float e = exp2f(fminf(z*2.885390082f, 80.f));
              float gl = vv * e * __builtin_amdgcn_rcpf(e + 1.0f);
              ((bf16*)outp)[(size_t)row*N + col] = __float2bfloat16(gl);
            } else {
              ((bf16*)outp)[(size_t)kz*M_*N + (size_t)row*N + col] = __float2bfloat16(vv);
            }
          }
        }
      }
    }
  }
}

// ---------------- Flash attention: K direct from global (L2-hit), V transposed in LDS ----------------
__global__ __launch_bounds__(512,4) void attn_k(const bf16* __restrict__ qkv,
    bf16* __restrict__ y)
{
  __shared__ unsigned short Vt[16*2048];   // 64 KB
  const int SQ = 3*C_;
  int tid = threadIdx.x, lane = tid&63, w = tid>>6;
  int b = blockIdx.z, h = blockIdx.y, qt = blockIdx.x;
  size_t baseQ = ((size_t)b*T_)*SQ + (size_t)h*64;
  size_t baseK = baseQ + 1024;
  size_t baseV = baseQ + 2048;
  size_t baseY = ((size_t)b*T_)*C_ + (size_t)h*64;

  #pragma unroll
  for (int i=0;i<8;i++){
    int cc = i*512 + tid;
    int tok = cc>>3, ch = cc&7;
    short8 vv = *reinterpret_cast<const short8*>(qkv + baseV + (size_t)tok*SQ + ch*8);
    int baseT = (tok>>5)*2048 + ch*256 + (tok&7);
    int ls = (tok&31)>>3;
    #pragma unroll
    for (int j=0;j<8;j++)
      Vt[baseT + j*32 + ((ls^(j&3))<<3)] = (unsigned short)vv[j];
  }
  __syncthreads();

  int g = lane>>4, r16 = lane&15;
  int qrow0 = qt*256 + w*32;
  short8 qf[2][2];
  #pragma unroll
  for (int s=0;s<2;s++)
    #pragma unroll
    for (int c=0;c<2;c++)
      qf[s][c] = *reinterpret_cast<const short8*>(qkv + baseQ + (size_t)(qrow0 + s*16 + r16)*SQ + c*32 + g*8);

  const f32x4 fz = {0.f,0.f,0.f,0.f};
  float mreg[2] = {-1e30f, -1e30f};
  float lsum[2] = {0.f, 0.f};
  f32x4 yacc[2][4];
  #pragma unroll
  for (int s=0;s<2;s++)
    #pragma unroll
    for (int dt=0;dt<4;dt++) yacc[s][dt] = fz;

  const float SC = 0.18033688011112043f; // (1/sqrt(64)) * log2(e)
  int rl0 = ((r16>>2)<<3) + (r16&3);     // k-row permutation so PV B-frag is lane-local
  const bf16* kb = qkv + baseK;
  const int vb0 = r16*32 + ((g ^ (r16&3))<<3);   // d=dt*16+r16 row base + swizzled slot

  for (int kt=0; kt<16; ++kt){
    int rowA = kt*32 + rl0;
    int rowB = rowA + 4;
    short8 kf0[2], kf1[2];
    #pragma unroll
    for (int c=0;c<2;c++){
      kf0[c] = *reinterpret_cast<const short8*>(kb + (size_t)rowA*SQ + c*32 + g*8);
      kf1[c] = *reinterpret_cast<const short8*>(kb + (size_t)rowB*SQ + c*32 + g*8);
    }
    short8 pf[2];
    #pragma unroll
    for (int s=0;s<2;s++){
      f32x4 st0 = fz, st1 = fz;
      st0 = __builtin_amdgcn_mfma_f32_16x16x32_bf16(kf0[0], qf[s][0], st0, 0,0,0);
      st0 = __builtin_amdgcn_mfma_f32_16x16x32_bf16(kf0[1], qf[s][1], st0, 0,0,0);
      st1 = __builtin_amdgcn_mfma_f32_16x16x32_bf16(kf1[0], qf[s][0], st1, 0,0,0);
      st1 = __builtin_amdgcn_mfma_f32_16x16x32_bf16(kf1[1], qf[s][1], st1, 0,0,0);
      float p0[4], p1[4];
      float tm = -1e30f;
      #pragma unroll
      for (int r=0;r<4;r++){
        p0[r] = st0[r]*SC; p1[r] = st1[r]*SC;
        tm = fmaxf(tm, fmaxf(p0[r], p1[r]));
      }
      tm = fmaxf(tm, __shfl_xor(tm, 16));
      tm = fmaxf(tm, __shfl_xor(tm, 32));
      float nm = fmaxf(mreg[s], tm);
      float f = exp2f(mreg[s] - nm);
      mreg[s] = nm;
      float psum = 0.f;
      #pragma unroll
      for (int r=0;r<4;r++){
        p0[r] = exp2f(p0[r]-nm); p1[r] = exp2f(p1[r]-nm);
        psum += p0[r] + p1[r];
      }
      lsum[s] = lsum[s]*f + psum;
      #pragma unroll
      for (int dt=0;dt<4;dt++) yacc[s][dt] *= f;
      short8 pp;
      pp[0]=f2bs(p0[0]); pp[1]=f2bs(p0[1]); pp[2]=f2bs(p0[2]); pp[3]=f2bs(p0[3]);
      pp[4]=f2bs(p1[0]); pp[5]=f2bs(p1[1]); pp[6]=f2bs(p1[2]); pp[7]=f2bs(p1[3]);
      pf[s] = pp;
    }
    #pragma unroll
    for (int dt=0;dt<4;dt++){
      short8 vfdt = *reinterpret_cast<const short8*>(&Vt[kt*2048 + dt*512 + vb0]);
      yacc[0][dt] = __builtin_amdgcn_mfma_f32_16x16x32_bf16(vfdt, pf[0], yacc[0][dt], 0,0,0);
      yacc[1][dt] = __builtin_amdgcn_mfma_f32_16x16x32_bf16(vfdt, pf[1], yacc[1][dt], 0,0,0);
    }
  }

  #pragma unroll
  for (int s=0;s<2;s++){
    float ls = lsum[s];
    ls += __shfl_xor(ls, 16);
    ls += __shfl_xor(ls, 32);
    float inv = 1.0f/ls;
    int qrow = qrow0 + s*16 + r16;
    #pragma unroll
    for (int dt=0;dt<4;dt++){
      ushort4 o;
      o.x = (unsigned short)f2bs(yacc[s][dt][0]*inv);
      o.y = (unsigned short)f2bs(yacc[s][dt][1]*inv);
      o.z = (unsigned short)f2bs(yacc[s][dt][2]*inv);
      o.w = (unsigned short)f2bs(yacc[s][dt][3]*inv);
      *reinterpret_cast<ushort4*>(y + baseY + (size_t)qrow*C_ + dt*16 + g*4) = o;
    }
  }
}

// ---------------- final LN (last token only, + W2 bf16 partials) + pooling head ----------------
__global__ __launch_bounds__(256) void head_k(const bf16* __restrict__ hbuf,
    const bf16* __restrict__ p0, const bf16* __restrict__ p1,
    const float* __restrict__ gf, const float* __restrict__ bfv,
    const float* __restrict__ Wp, const float* __restrict__ bp, float* __restrict__ out)
{
  int b = blockIdx.x, kc = blockIdx.y, tid = threadIdx.x;
  int w = tid >> 6, lane = tid & 63;
  size_t base = ((size_t)(b*T_ + T_-1))*C_;
  ushort4 hv = reinterpret_cast<const ushort4*>(hbuf + base)[tid];
  ushort4 a = reinterpret_cast<const ushort4*>(p0 + base)[tid];
  ushort4 c = reinterpret_cast<const ushort4*>(p1 + base)[tid];
  float vx = bs2f(hv.x) + bs2f(a.x) + bs2f(c.x);
  float vy = bs2f(hv.y) + bs2f(a.y) + bs2f(c.y);
  float vz = bs2f(hv.z) + bs2f(a.z) + bs2f(c.z);
  float vw = bs2f(hv.w) + bs2f(a.w) + bs2f(c.w);
  float s = vx+vy+vz+vw;
  float ss = vx*vx+vy*vy+vz*vz+vw*vw;
  #pragma unroll
  for (int o=32;o>=1;o>>=1){ s += __shfl_xor(s,o); ss += __shfl_xor(ss,o); }
  __shared__ float sa[4], sb[4];
  if (lane==0){ sa[w]=s; sb[w]=ss; }
  __syncthreads();
  s  = sa[0]+sa[1]+sa[2]+sa[3];
  ss = sb[0]+sb[1]+sb[2]+sb[3];
  float mean = s * (1.0f/C_);
  float var  = ss * (1.0f/C_) - mean*mean;
  float rs = rsqrtf(var + 1e-5f);
  __shared__ float nrm[C_];
  float4 gv = reinterpret_cast<const float4*>(gf)[tid];
  float4 bv = reinterpret_cast<const float4*>(bfv)[tid];
  nrm[tid*4+0] = (vx-mean)*rs*gv.x + bv.x;
  nrm[tid*4+1] = (vy-mean)*rs*gv.y + bv.y;
  nrm[tid*4+2] = (vz-mean)*rs*gv.z + bv.z;
  nrm[tid*4+3] = (vw-mean)*rs*gv.w + bv.w;
  __syncthreads();
  float acc = (kc==0) ? bp[tid] : 0.f;
  int k0 = kc*64;
  #pragma unroll 8
  for (int kk=k0; kk<k0+64; kk++) acc += nrm[kk]*Wp[(size_t)kk*256 + tid];
  atomicAdd(&out[b*256 + tid], acc);
}

extern "C" void kernel_launch(void* const* d_in, const int* in_sizes, int n_in,
                              void* d_out, int out_size, void* d_ws, size_t ws_size,
                              hipStream_t stream)
{
  const float* x  = (const float*)d_in[0];
  const float* Wq = (const float*)d_in[1];
  const float* bq = (const float*)d_in[2];
  const float* Wk = (const float*)d_in[3];
  const float* bk = (const float*)d_in[4];
  const float* Wv = (const float*)d_in[5];
  const float* bv = (const float*)d_in[6];
  const float* Wo = (const float*)d_in[7];
  const float* bo = (const float*)d_in[8];
  const float* g1 = (const float*)d_in[9];
  const float* be1= (const float*)d_in[10];
  const float* g2 = (const float*)d_in[11];
  const float* be2= (const float*)d_in[12];
  const float* W1 = (const float*)d_in[13];
  const float* b1 = (const float*)d_in[14];
  const float* W2 = (const float*)d_in[15];
  const float* b2 = (const float*)d_in[16];
  const float* gf = (const float*)d_in[17];
  const float* bfv= (const float*)d_in[18];
  const float* Wp = (const float*)d_in[19];
  const float* bp = (const float*)d_in[20];
  float* out = (float*)d_out;

  const size_t NEED = 209715200;
  if (ws_size < NEED) return;

  char* ws = (char*)d_ws;
  bf16* hbuf  = (bf16*)ws;                       //   0 .. 16MiB  bf16 residual
  bf16* abuf  = (bf16*)(ws + 33554432);          //  32 .. 48MiB
  bf16* qkv   = (bf16*)(ws + 50331648);          //  48 .. 96MiB   [M,3C] (aliased by mid)
  bf16* ybuf  = (bf16*)(ws + 100663296);         //  96 ..112MiB   (aliased by mid)
  bf16* mid   = (bf16*)(ws + 50331648);          //  48 ..112MiB   [M,F]
  bf16* slab  = (bf16*)(ws + 117440512);         // 112 ..136MiB   per-layer bf16 Wt
  bf16* part  = (bf16*)(ws + 142606336);         // 136 ..168MiB   2x [M,C] bf16 split-K partials

  cvt_x<<<8192, 256, 0, stream>>>(x, hbuf);
  hipMemsetAsync(d_out, 0, (size_t)out_size*sizeof(float), stream);

  for (int l=0; l<L_; ++l){
    size_t oCC = (size_t)l*C_*C_, oC = (size_t)l*C_;
    size_t oCF = (size_t)l*C_*F_, oF = (size_t)l*F_;
    convert_w<<<12288, 256, 0, stream>>>(Wq+oCC, Wk+oCC, Wv+oCC, Wo+oCC, W1+oCF, W2+oCF, slab);
    // ln1: fold in previous layer's W2 partials (none at l==0)
    ln_k<<<M_, 256, 0, stream>>>(hbuf, part, part + (size_t)M_*C_, l>0 ? 1:0, g1+oC, be1+oC, abuf);
    // fused QKV: [8192,1024] @ [3072,1024]^T -> [8192,3072]
    gemmd_k<0,1><<<dim3(12,32), 512, 0, stream>>>(abuf, C_, slab, C_,
        bq+oC, bk+oC, bv+oC, 1, qkv, 3*C_, C_);
    attn_k<<<dim3(2, H_, B_), 512, 0, stream>>>(qkv, ybuf);
    // Wo: split-K=2 -> bf16 partials
    gemmd_k<2,0><<<dim3(4,32,2), 512, 0, stream>>>(ybuf, C_, slab + (size_t)3*C_*C_, C_,
        bo+oC, bo+oC, bo+oC, 1, part, C_, C_/2);
    // ln2: fold in Wo partials
    ln_k<<<M_, 256, 0, stream>>>(hbuf, part, part + (size_t)M_*C_, 1, g2+oC, be2+oC, abuf);
    // W1: [8192,1024] @ [4096,1024]^T -> GELU -> [8192,4096]
    gemmd_k<1,0><<<dim3(16,32), 512, 0, stream>>>(abuf, C_, slab + (size_t)4*C_*C_, C_,
        b1+oF, b1+oF, b1+oF, 1, mid, F_, C_);
    // W2: split-K=2 -> bf16 partials (folded by next ln1 / head)
    gemmd_k<2,0><<<dim3(4,32,2), 512, 0, stream>>>(mid, F_, slab + (size_t)4*C_*C_ + (size_t)C_*F_, F_,
        b2+oC, b2+oC, b2+oC, 1, part, C_, F_/2);
  }
  head_k<<<dim3(B_,16), 256, 0, stream>>>(hbuf, part, part + (size_t)M_*C_,
      gf, bfv, Wp, bp, out);
}

// Round 15
// 2558.723 us; speedup vs baseline: 2.1959x; 2.1959x over previous
//
#include <hip/hip_runtime.h>
#include <hip/hip_bf16.h>
#include <math.h>

#define B_ 16
#define T_ 512
#define C_ 1024
#define H_ 16
#define D_ 64
#define F_ 4096
#define L_ 8
#define M_ (B_*T_)   // 8192 rows

typedef __hip_bfloat16 bf16;
typedef __attribute__((ext_vector_type(8))) short short8;
typedef __attribute__((ext_vector_type(4))) float f32x4;

__device__ __forceinline__ short f2bs(float x){
  union { __hip_bfloat16 h; short s; } u;
  u.h = __float2bfloat16(x);
  return u.s;
}
__device__ __forceinline__ float bs2f(unsigned short s){
  union { float f; unsigned u; } v; v.u = ((unsigned)s) << 16; return v.f;
}

__device__ __forceinline__ void gload16(const void* g, void* l){
  __builtin_amdgcn_global_load_lds((const __attribute__((address_space(1))) void*)g,
      (__attribute__((address_space(3))) void*)l, 16, 0, 0);
}

// ---------------- x f32 -> h bf16 ----------------
__global__ __launch_bounds__(256) void cvt_x(const float* __restrict__ x, bf16* __restrict__ h){
  int i = blockIdx.x*256 + threadIdx.x;
  float4 v = reinterpret_cast<const float4*>(x)[i];
  ushort4 o;
  o.x = (unsigned short)f2bs(v.x); o.y = (unsigned short)f2bs(v.y);
  o.z = (unsigned short)f2bs(v.z); o.w = (unsigned short)f2bs(v.w);
  reinterpret_cast<ushort4*>(h)[i] = o;
}

// ---------------- weight transpose+convert: W[K,N] f32 -> Wt[N,K] bf16 ----------------
__global__ __launch_bounds__(256) void convert_w(
    const float* __restrict__ Wq, const float* __restrict__ Wk,
    const float* __restrict__ Wv, const float* __restrict__ Wo,
    const float* __restrict__ W1, const float* __restrict__ W2,
    bf16* __restrict__ slab)
{
  __shared__ float t[32][33];
  int bid = blockIdx.x;
  const float* src; bf16* dst; int K, N, tile;
  if (bid < 4096) {
    int m = bid >> 10;
    src = (m==0)?Wq:(m==1)?Wk:(m==2)?Wv:Wo;
    dst = slab + (size_t)m*C_*C_;
    K = C_; N = C_; tile = bid & 1023;
  } else if (bid < 8192) {
    src = W1; dst = slab + (size_t)4*C_*C_; K = C_; N = F_; tile = bid - 4096;
  } else {
    src = W2; dst = slab + (size_t)4*C_*C_ + (size_t)C_*F_; K = F_; N = C_; tile = bid - 8192;
  }
  int tilesN = N >> 5;
  int tk = tile / tilesN, tn = tile % tilesN;
  int r = threadIdx.x >> 5, c = threadIdx.x & 31;
  #pragma unroll
  for (int i=0;i<4;i++)
    t[r + i*8][c] = src[(size_t)(tk*32 + r + i*8)*N + tn*32 + c];
  __syncthreads();
  #pragma unroll
  for (int i=0;i<4;i++)
    dst[(size_t)(tn*32 + r + i*8)*K + tk*32 + c] = __float2bfloat16(t[c][r + i*8]);
}

// ---------------- LayerNorm on bf16 residual (+optional bf16 split-K partial fold) ----------------
// v = h + (hasP ? p0+p1 : 0) in f32; if hasP: h <- bf16(v); out = LN(v)*g+be (bf16)
__global__ __launch_bounds__(256) void ln_k(bf16* __restrict__ h,
    const bf16* __restrict__ p0, const bf16* __restrict__ p1, int hasP,
    const float* __restrict__ g, const float* __restrict__ be, bf16* __restrict__ out)
{
  int row = blockIdx.x;
  int tid = threadIdx.x;
  int w = tid >> 6, lane = tid & 63;
  size_t base = (size_t)row*C_;
  ushort4 hv = reinterpret_cast<const ushort4*>(h + base)[tid];
  float vx = bs2f(hv.x), vy = bs2f(hv.y), vz = bs2f(hv.z), vw = bs2f(hv.w);
  if (hasP){
    ushort4 a = reinterpret_cast<const ushort4*>(p0 + base)[tid];
    ushort4 b = reinterpret_cast<const ushort4*>(p1 + base)[tid];
    vx += bs2f(a.x) + bs2f(b.x); vy += bs2f(a.y) + bs2f(b.y);
    vz += bs2f(a.z) + bs2f(b.z); vw += bs2f(a.w) + bs2f(b.w);
    ushort4 hw;
    hw.x = (unsigned short)f2bs(vx); hw.y = (unsigned short)f2bs(vy);
    hw.z = (unsigned short)f2bs(vz); hw.w = (unsigned short)f2bs(vw);
    reinterpret_cast<ushort4*>(h + base)[tid] = hw;
  }
  float s = vx+vy+vz+vw;
  float ss = vx*vx+vy*vy+vz*vz+vw*vw;
  #pragma unroll
  for (int o=32;o>=1;o>>=1){ s += __shfl_xor(s,o); ss += __shfl_xor(ss,o); }
  __shared__ float sa[4], sb[4];
  if (lane==0){ sa[w]=s; sb[w]=ss; }
  __syncthreads();
  s  = sa[0]+sa[1]+sa[2]+sa[3];
  ss = sb[0]+sb[1]+sb[2]+sb[3];
  float mean = s * (1.0f/C_);
  float var  = ss * (1.0f/C_) - mean*mean;
  float rs = rsqrtf(var + 1e-5f);
  float4 gv = reinterpret_cast<const float4*>(g)[tid];
  float4 bv = reinterpret_cast<const float4*>(be)[tid];
  ushort4 o;
  o.x = (unsigned short)f2bs((vx-mean)*rs*gv.x + bv.x);
  o.y = (unsigned short)f2bs((vy-mean)*rs*gv.y + bv.y);
  o.z = (unsigned short)f2bs((vz-mean)*rs*gv.z + bv.z);
  o.w = (unsigned short)f2bs((vw-mean)*rs*gv.w + bv.w);
  reinterpret_cast<ushort4*>(out + base)[tid] = o;
}

// ---------------- 256x256 GEMM, fat 2-phase/K-tile, counted vmcnt (r7 best config) ----------------
// EPI: 0 = bf16+bias, 1 = tanh-GELU bf16+bias, 2 = bf16 partial store (+bias when kz==0)
template<int EPI, int QKV3>
__global__ __launch_bounds__(512,1) void gemm8_k(
    const bf16* __restrict__ A, int lda,
    const bf16* __restrict__ Bt, int ldb,
    const float* __restrict__ b0, const float* __restrict__ b1v,
    const float* __restrict__ b2v, int addbias,
    void* __restrict__ outp, int N, int Ksub)
{
  __shared__ char lds[131072];
  // slot byte offsets: Ae=0, Be=32768, Ao=65536, Bo=98304; halves at +0/+16384

  const int tid = threadIdx.x, lane = tid & 63;
  const int w = tid >> 6, wr = w >> 2, wc = w & 3;
  const int r16 = lane & 15, g = lane >> 4, l7 = lane & 7;

  // bijective XCD swizzle (all grids here have nwg % 8 == 0)
  int bid = blockIdx.y * gridDim.x + blockIdx.x;
  int cpx = (gridDim.x * gridDim.y) >> 3;
  int swz = (bid & 7) * cpx + (bid >> 3);
  int tn = swz % gridDim.x, tm = swz / gridDim.x;
  const int R0 = tm * 256, C0 = tn * 256;
  const int kz = blockIdx.z;
  const bf16* Ab = A  + (size_t)kz * Ksub;
  const bf16* Bb = Bt + (size_t)kz * Ksub;
  const int KT = Ksub >> 6;   // even, >= 4

  // staging: scalar row-bases + per-lane 32-bit offset (source-side XOR swizzle)
  const int rS = tid >> 3;
  const int cS = (tid & 7) ^ (rS & 7);
  const int offLa = rS * lda + cS * 8;
  const int offLb = rS * ldb + cS * 8;
  const int ld64a = lda << 6, ld64b = ldb << 6;
  const bf16* pA0 = Ab + (size_t)R0 * lda;
  const bf16* pA1 = pA0 + ((size_t)lda << 7);
  const bf16* pB0 = Bb + (size_t)C0 * ldb;
  const bf16* pB1 = pB0 + ((size_t)ldb << 7);

#define STG(slotOff, pb, ld64, offv, tile) { \
    int ut_ = (tile) < KT ? (tile) : KT-1; \
    const bf16* q_ = (pb) + (size_t)(ut_ << 6); \
    gload16(q_ + (offv), &lds[(slotOff) + tid*16]); \
    gload16(q_ + (offv) + (ld64), &lds[(slotOff) + 8192 + tid*16]); }

  // LDS read offsets (XOR swizzle folded in); all reads: &lds[const + off]
  int aOff[2], bOff[2];
  #pragma unroll
  for (int k=0;k<2;k++){
    int cl = ((((k<<2)+g) ^ l7) << 4);
    aOff[k] = ((wr*64 + r16) << 7) + cl;
    bOff[k] = ((wc*32 + r16) << 7) + cl;
  }

  // prologue: tile0 [Be0,Ae0,Be1,Ae1], tile1 [Bo0,Ao0]  (12 loads)
  STG(32768,       pB0, ld64b, offLb, 0)
  STG(0,           pA0, ld64a, offLa, 0)
  STG(32768+16384, pB1, ld64b, offLb, 0)
  STG(16384,       pA1, ld64a, offLa, 0)
  STG(98304,       pB0, ld64b, offLb, 1)
  STG(65536,       pA0, ld64a, offLa, 1)
  asm volatile("s_waitcnt vmcnt(6)" ::: "memory");
  __builtin_amdgcn_s_barrier();

  const f32x4 fz = {0.f,0.f,0.f,0.f};
  f32x4 acc[8][4];
  #pragma unroll
  for (int m=0;m<8;m++){
    #pragma unroll
    for (int n=0;n<4;n++) acc[m][n] = fz;
  }

  short8 af[4][2];        // current A half-quadrant frags
  short8 bA[2][2][2];     // full B set for current K-tile: [nh][n][k]

#define LOADA(mh, EO) { \
    _Pragma("unroll") \
    for (int m=0;m<4;m++){ \
      _Pragma("unroll") \
      for (int k=0;k<2;k++) \
        af[m][k] = *reinterpret_cast<const short8*>(&lds[(EO) + (mh)*16384 + m*2048 + aOff[k]]); } }
#define LOADBALL(EO) { \
    _Pragma("unroll") \
    for (int nh=0;nh<2;nh++){ \
      _Pragma("unroll") \
      for (int n=0;n<2;n++){ \
        _Pragma("unroll") \
        for (int k=0;k<2;k++) \
          bA[nh][n][k] = *reinterpret_cast<const short8*>(&lds[32768 + (EO) + nh*16384 + n*2048 + bOff[k]]); } } }
// 32 MFMA, k-outer so the k=0/k=1 dependent pairs are 16 apart
#define MM2(mh) { \
    __builtin_amdgcn_s_setprio(1); \
    _Pragma("unroll") \
    for (int k=0;k<2;k++){ \
      _Pragma("unroll") \
      for (int m=0;m<4;m++){ \
        _Pragma("unroll") \
        for (int nh=0;nh<2;nh++){ \
          _Pragma("unroll") \
          for (int n=0;n<2;n++) \
            acc[(mh)*4+m][nh*2+n] = __builtin_amdgcn_mfma_f32_16x16x32_bf16( \
                af[m][k], bA[nh][n][k], acc[(mh)*4+m][nh*2+n], 0,0,0); } } } \
    __builtin_amdgcn_s_setprio(0); }
#define BAR __builtin_amdgcn_s_barrier()
#define WV8 asm volatile("s_waitcnt vmcnt(8)" ::: "memory")
#define WV6 asm volatile("s_waitcnt vmcnt(6)" ::: "memory")

  for (int it=0; it<KT/2; ++it){
    int u = 2*it;
    // phA even: A-h0 + B-all of tile u; stage [Bo1,Ao1] <- u+1
    LOADA(0,0) LOADBALL(0)
    STG(98304+16384, pB1, ld64b, offLb, u+1)
    STG(65536+16384, pA1, ld64a, offLa, u+1)
    BAR; MM2(0) WV8; BAR;
    // phB even: A-h1 of tile u; stage [Be0,Ae0] <- u+2
    LOADA(1,0)
    STG(32768,       pB0, ld64b, offLb, u+2)
    STG(0,           pA0, ld64a, offLa, u+2)
    BAR; MM2(1) WV6; BAR;
    // phA odd: tile u+1; stage [Be1,Ae1] <- u+2
    LOADA(0,65536) LOADBALL(65536)
    STG(32768+16384, pB1, ld64b, offLb, u+2)
    STG(16384,       pA1, ld64a, offLa, u+2)
    BAR; MM2(0) WV8; BAR;
    // phB odd: stage [Bo0,Ao0] <- u+3
    LOADA(1,65536)
    STG(98304,       pB0, ld64b, offLb, u+3)
    STG(65536,       pA0, ld64a, offLa, u+3)
    BAR; MM2(1) WV6; BAR;
  }
  asm volatile("s_waitcnt vmcnt(0)" ::: "memory");
#undef LOADA
#undef LOADBALL
#undef MM2
#undef BAR
#undef WV8
#undef WV6
#undef STG

  // epilogue
  int sel = C0 >> 10;
  const float* bp = QKV3 ? (sel==0 ? b0 : (sel==1 ? b1v : b2v)) : b0;
  int cb0 = QKV3 ? (C0 & 1023) : C0;
  int ab = addbias && (kz == 0);
  #pragma unroll
  for (int mh=0; mh<2; mh++){
    #pragma unroll
    for (int m=0;m<4;m++){
      #pragma unroll
      for (int nh=0; nh<2; nh++){
        #pragma unroll
        for (int n=0;n<2;n++){
          int colrel = nh*128 + wc*32 + n*16 + r16;
          int col = C0 + colrel;
          float bb = ab ? bp[cb0 + colrel] : 0.f;
          #pragma unroll
          for (int r=0;r<4;r++){
            int row = R0 + mh*128 + wr*64 + m*16 + g*4 + r;
            float vv = acc[mh*4+m][nh*2+n][r] + bb;
            if (EPI==0){
              ((bf16*)outp)[(size_t)row*N + col] = __float2bfloat16(vv);
            } else if (EPI==1){
              float z = 0.7978845608f*(vv + 0.044715f*vv*vv*vv);
              float e = exp2f(fminf(z*2.885390082f, 80.f));
              float gl = vv * e * __builtin_amdgcn_rcpf(e + 1.0f);
              ((bf16*)outp)[(size_t)row*N + col] = __float2bfloat16(gl);
            } else {
              ((bf16*)outp)[(size_t)kz*M_*N + (size_t)row*N + col] = __float2bfloat16(vv);
            }
          }
        }
      }
    }
  }
}

// ---------------- Flash attention: K direct from global (L2-hit), V transposed in LDS ----------------
__global__ __launch_bounds__(512,4) void attn_k(const bf16* __restrict__ qkv,
    bf16* __restrict__ y)
{
  __shared__ unsigned short Vt[16*2048];   // 64 KB
  const int SQ = 3*C_;
  int tid = threadIdx.x, lane = tid&63, w = tid>>6;
  int b = blockIdx.z, h = blockIdx.y, qt = blockIdx.x;
  size_t baseQ = ((size_t)b*T_)*SQ + (size_t)h*64;
  size_t baseK = baseQ + 1024;
  size_t baseV = baseQ + 2048;
  size_t baseY = ((size_t)b*T_)*C_ + (size_t)h*64;

  #pragma unroll
  for (int i=0;i<8;i++){
    int cc = i*512 + tid;
    int tok = cc>>3, ch = cc&7;
    short8 vv = *reinterpret_cast<const short8*>(qkv + baseV + (size_t)tok*SQ + ch*8);
    int baseT = (tok>>5)*2048 + ch*256 + (tok&7);
    int ls = (tok&31)>>3;
    #pragma unroll
    for (int j=0;j<8;j++)
      Vt[baseT + j*32 + ((ls^(j&3))<<3)] = (unsigned short)vv[j];
  }
  __syncthreads();

  int g = lane>>4, r16 = lane&15;
  int qrow0 = qt*256 + w*32;
  short8 qf[2][2];
  #pragma unroll
  for (int s=0;s<2;s++)
    #pragma unroll
    for (int c=0;c<2;c++)
      qf[s][c] = *reinterpret_cast<const short8*>(qkv + baseQ + (size_t)(qrow0 + s*16 + r16)*SQ + c*32 + g*8);

  const f32x4 fz = {0.f,0.f,0.f,0.f};
  float mreg[2] = {-1e30f, -1e30f};
  float lsum[2] = {0.f, 0.f};
  f32x4 yacc[2][4];
  #pragma unroll
  for (int s=0;s<2;s++)
    #pragma unroll
    for (int dt=0;dt<4;dt++) yacc[s][dt] = fz;

  const float SC = 0.18033688011112043f; // (1/sqrt(64)) * log2(e)
  int rl0 = ((r16>>2)<<3) + (r16&3);     // k-row permutation so PV B-frag is lane-local
  const bf16* kb = qkv + baseK;
  const int vb0 = r16*32 + ((g ^ (r16&3))<<3);   // d=dt*16+r16 row base + swizzled slot

  for (int kt=0; kt<16; ++kt){
    int rowA = kt*32 + rl0;
    int rowB = rowA + 4;
    short8 kf0[2], kf1[2];
    #pragma unroll
    for (int c=0;c<2;c++){
      kf0[c] = *reinterpret_cast<const short8*>(kb + (size_t)rowA*SQ + c*32 + g*8);
      kf1[c] = *reinterpret_cast<const short8*>(kb + (size_t)rowB*SQ + c*32 + g*8);
    }
    short8 pf[2];
    #pragma unroll
    for (int s=0;s<2;s++){
      f32x4 st0 = fz, st1 = fz;
      st0 = __builtin_amdgcn_mfma_f32_16x16x32_bf16(kf0[0], qf[s][0], st0, 0,0,0);
      st0 = __builtin_amdgcn_mfma_f32_16x16x32_bf16(kf0[1], qf[s][1], st0, 0,0,0);
      st1 = __builtin_amdgcn_mfma_f32_16x16x32_bf16(kf1[0], qf[s][0], st1, 0,0,0);
      st1 = __builtin_amdgcn_mfma_f32_16x16x32_bf16(kf1[1], qf[s][1], st1, 0,0,0);
      float p0[4], p1[4];
      float tm = -1e30f;
      #pragma unroll
      for (int r=0;r<4;r++){
        p0[r] = st0[r]*SC; p1[r] = st1[r]*SC;
        tm = fmaxf(tm, fmaxf(p0[r], p1[r]));
      }
      tm = fmaxf(tm, __shfl_xor(tm, 16));
      tm = fmaxf(tm, __shfl_xor(tm, 32));
      float nm = fmaxf(mreg[s], tm);
      float f = exp2f(mreg[s] - nm);
      mreg[s] = nm;
      float psum = 0.f;
      #pragma unroll
      for (int r=0;r<4;r++){
        p0[r] = exp2f(p0[r]-nm); p1[r] = exp2f(p1[r]-nm);
        psum += p0[r] + p1[r];
      }
      lsum[s] = lsum[s]*f + psum;
      #pragma unroll
      for (int dt=0;dt<4;dt++) yacc[s][dt] *= f;
      short8 pp;
      pp[0]=f2bs(p0[0]); pp[1]=f2bs(p0[1]); pp[2]=f2bs(p0[2]); pp[3]=f2bs(p0[3]);
      pp[4]=f2bs(p1[0]); pp[5]=f2bs(p1[1]); pp[6]=f2bs(p1[2]); pp[7]=f2bs(p1[3]);
      pf[s] = pp;
    }
    #pragma unroll
    for (int dt=0;dt<4;dt++){
      short8 vfdt = *reinterpret_cast<const short8*>(&Vt[kt*2048 + dt*512 + vb0]);
      yacc[0][dt] = __builtin_amdgcn_mfma_f32_16x16x32_bf16(vfdt, pf[0], yacc[0][dt], 0,0,0);
      yacc[1][dt] = __builtin_amdgcn_mfma_f32_16x16x32_bf16(vfdt, pf[1], yacc[1][dt], 0,0,0);
    }
  }

  #pragma unroll
  for (int s=0;s<2;s++){
    float ls = lsum[s];
    ls += __shfl_xor(ls, 16);
    ls += __shfl_xor(ls, 32);
    float inv = 1.0f/ls;
    int qrow = qrow0 + s*16 + r16;
    #pragma unroll
    for (int dt=0;dt<4;dt++){
      ushort4 o;
      o.x = (unsigned short)f2bs(yacc[s][dt][0]*inv);
      o.y = (unsigned short)f2bs(yacc[s][dt][1]*inv);
      o.z = (unsigned short)f2bs(yacc[s][dt][2]*inv);
      o.w = (unsigned short)f2bs(yacc[s][dt][3]*inv);
      *reinterpret_cast<ushort4*>(y + baseY + (size_t)qrow*C_ + dt*16 + g*4) = o;
    }
  }
}

// ---------------- final LN (last token only, + W2 bf16 partials) + pooling head ----------------
__global__ __launch_bounds__(256) void head_k(const bf16* __restrict__ hbuf,
    const bf16* __restrict__ p0, const bf16* __restrict__ p1,
    const float* __restrict__ gf, const float* __restrict__ bfv,
    const float* __restrict__ Wp, const float* __restrict__ bp, float* __restrict__ out)
{
  int b = blockIdx.x, kc = blockIdx.y, tid = threadIdx.x;
  int w = tid >> 6, lane = tid & 63;
  size_t base = ((size_t)(b*T_ + T_-1))*C_;
  ushort4 hv = reinterpret_cast<const ushort4*>(hbuf + base)[tid];
  ushort4 a = reinterpret_cast<const ushort4*>(p0 + base)[tid];
  ushort4 c = reinterpret_cast<const ushort4*>(p1 + base)[tid];
  float vx = bs2f(hv.x) + bs2f(a.x) + bs2f(c.x);
  float vy = bs2f(hv.y) + bs2f(a.y) + bs2f(c.y);
  float vz = bs2f(hv.z) + bs2f(a.z) + bs2f(c.z);
  float vw = bs2f(hv.w) + bs2f(a.w) + bs2f(c.w);
  float s = vx+vy+vz+vw;
  float ss = vx*vx+vy*vy+vz*vz+vw*vw;
  #pragma unroll
  for (int o=32;o>=1;o>>=1){ s += __shfl_xor(s,o); ss += __shfl_xor(ss,o); }
  __shared__ float sa[4], sb[4];
  if (lane==0){ sa[w]=s; sb[w]=ss; }
  __syncthreads();
  s  = sa[0]+sa[1]+sa[2]+sa[3];
  ss = sb[0]+sb[1]+sb[2]+sb[3];
  float mean = s * (1.0f/C_);
  float var  = ss * (1.0f/C_) - mean*mean;
  float rs = rsqrtf(var + 1e-5f);
  __shared__ float nrm[C_];
  float4 gv = reinterpret_cast<const float4*>(gf)[tid];
  float4 bv = reinterpret_cast<const float4*>(bfv)[tid];
  nrm[tid*4+0] = (vx-mean)*rs*gv.x + bv.x;
  nrm[tid*4+1] = (vy-mean)*rs*gv.y + bv.y;
  nrm[tid*4+2] = (vz-mean)*rs*gv.z + bv.z;
  nrm[tid*4+3] = (vw-mean)*rs*gv.w + bv.w;
  __syncthreads();
  float acc = (kc==0) ? bp[tid] : 0.f;
  int k0 = kc*64;
  #pragma unroll 8
  for (int kk=k0; kk<k0+64; kk++) acc += nrm[kk]*Wp[(size_t)kk*256 + tid];
  atomicAdd(&out[b*256 + tid], acc);
}

extern "C" void kernel_launch(void* const* d_in, const int* in_sizes, int n_in,
                              void* d_out, int out_size, void* d_ws, size_t ws_size,
                              hipStream_t stream)
{
  const float* x  = (const float*)d_in[0];
  const float* Wq = (const float*)d_in[1];
  const float* bq = (const float*)d_in[2];
  const float* Wk = (const float*)d_in[3];
  const float* bk = (const float*)d_in[4];
  const float* Wv = (const float*)d_in[5];
  const float* bv = (const float*)d_in[6];
  const float* Wo = (const float*)d_in[7];
  const float* bo = (const float*)d_in[8];
  const float* g1 = (const float*)d_in[9];
  const float* be1= (const float*)d_in[10];
  const float* g2 = (const float*)d_in[11];
  const float* be2= (const float*)d_in[12];
  const float* W1 = (const float*)d_in[13];
  const float* b1 = (const float*)d_in[14];
  const float* W2 = (const float*)d_in[15];
  const float* b2 = (const float*)d_in[16];
  const float* gf = (const float*)d_in[17];
  const float* bfv= (const float*)d_in[18];
  const float* Wp = (const float*)d_in[19];
  const float* bp = (const float*)d_in[20];
  float* out = (float*)d_out;

  const size_t NEED = 209715200;
  if (ws_size < NEED) return;

  char* ws = (char*)d_ws;
  bf16* hbuf  = (bf16*)ws;                       //   0 .. 16MiB  bf16 residual
  bf16* abuf  = (bf16*)(ws + 33554432);          //  32 .. 48MiB
  bf16* qkv   = (bf16*)(ws + 50331648);          //  48 .. 96MiB   [M,3C] (aliased by mid)
  bf16* ybuf  = (bf16*)(ws + 100663296);         //  96 ..112MiB   (aliased by mid)
  bf16* mid   = (bf16*)(ws + 50331648);          //  48 ..112MiB   [M,F]
  bf16* slab  = (bf16*)(ws + 117440512);         // 112 ..136MiB   per-layer bf16 Wt
  bf16* part  = (bf16*)(ws + 142606336);         // 136 ..168MiB   2x [M,C] bf16 split-K partials

  cvt_x<<<8192, 256, 0, stream>>>(x, hbuf);
  hipMemsetAsync(d_out, 0, (size_t)out_size*sizeof(float), stream);

  for (int l=0; l<L_; ++l){
    size_t oCC = (size_t)l*C_*C_, oC = (size_t)l*C_;
    size_t oCF = (size_t)l*C_*F_, oF = (size_t)l*F_;
    convert_w<<<12288, 256, 0, stream>>>(Wq+oCC, Wk+oCC, Wv+oCC, Wo+oCC, W1+oCF, W2+oCF, slab);
    // ln1: fold in previous layer's W2 partials (none at l==0)
    ln_k<<<M_, 256, 0, stream>>>(hbuf, part, part + (size_t)M_*C_, l>0 ? 1:0, g1+oC, be1+oC, abuf);
    // fused QKV: [8192,1024] @ [3072,1024]^T -> [8192,3072]
    gemm8_k<0,1><<<dim3(12,32), 512, 0, stream>>>(abuf, C_, slab, C_,
        bq+oC, bk+oC, bv+oC, 1, qkv, 3*C_, C_);
    attn_k<<<dim3(2, H_, B_), 512, 0, stream>>>(qkv, ybuf);
    // Wo: split-K=2 -> bf16 partials
    gemm8_k<2,0><<<dim3(4,32,2), 512, 0, stream>>>(ybuf, C_, slab + (size_t)3*C_*C_, C_,
        bo+oC, bo+oC, bo+oC, 1, part, C_, C_/2);
    // ln2: fold in Wo partials
    ln_k<<<M_, 256, 0, stream>>>(hbuf, part, part + (size_t)M_*C_, 1, g2+oC, be2+oC, abuf);
    // W1: [8192,1024] @ [4096,1024]^T -> GELU -> [8192,4096]
    gemm8_k<1,0><<<dim3(16,32), 512, 0, stream>>>(abuf, C_, slab + (size_t)4*C_*C_, C_,
        b1+oF, b1+oF, b1+oF, 1, mid, F_, C_);
    // W2: split-K=2 -> bf16 partials (folded by next ln1 / head)
    gemm8_k<2,0><<<dim3(4,32,2), 512, 0, stream>>>(mid, F_, slab + (size_t)4*C_*C_ + (size_t)C_*F_, F_,
        b2+oC, b2+oC, b2+oC, 1, part, C_, F_/2);
  }
  head_k<<<dim3(B_,16), 256, 0, stream>>>(hbuf, part, part + (size_t)M_*C_,
      gf, bfv, Wp, bp, out);
}